// Round 9
// baseline (305.491 us; speedup 1.0000x reference)
//
#include <hip/hip_runtime.h>
#include <math.h>

#define CH 64
#define S 64
#define S2 (64 * 64)
#define S3 (64 * 64 * 64)

__device__ float WT_buf[CH * CH];  // W transposed: WT[c][o]

// ---------------------------------------------------------------------------
// Kernel 0: transpose W (64x64) into WT_buf (columns of W become contiguous
// rows -> wide scalar loads in the fused kernel's W-accumulation).
// ---------------------------------------------------------------------------
__global__ __launch_bounds__(256) void wtrans(const float* __restrict__ W) {
  int i = blockIdx.x * 256 + threadIdx.x;
  int o = i >> 6, c = i & 63;
  WT_buf[c * CH + o] = W[o * CH + c];
}

// ---------------------------------------------------------------------------
// Fused kernel: scores -> softmax -> V-gather -> W-projection -> out, one
// pass, barrier-free, LDS-free. One wave per (b,d,h) row; lane = w.
//
// r8 lesson (rule #20): the epilogue's partial unroll made acc_o[o]
// runtime-indexed -> whole array in scratch (VGPR=68, 256 MB spill writes).
// Everything touching acc_o is now FULLY unrolled; __launch_bounds__(256,3)
// caps VGPR at ~170 so the allocator keeps it in registers (live ~140).
// ---------------------------------------------------------------------------
__global__ __launch_bounds__(256, 3) void attn_fused(const float* __restrict__ Q,
                                                     const float* __restrict__ K,
                                                     const float* __restrict__ V,
                                                     const float* __restrict__ pe,
                                                     const float* __restrict__ bias,
                                                     float* __restrict__ out) {
  int tid = threadIdx.x;
  int lane = tid & 63;
  int wv = tid >> 6;

  // XCD-aware bijective swizzle (2048 % 8 == 0)
  int raw = blockIdx.x;
  int sw = (raw & 7) * 256 + (raw >> 3);
  int b = sw >> 10;
  int r = sw & 1023;
  int d = r >> 4;                                             // 0..63
  int hu = __builtin_amdgcn_readfirstlane((r & 15) * 4 + wv);  // 0..63, uniform

  size_t bbase = (size_t)b << 24;
  const float* Qb = Q + bbase;
  const float* Kb = K + bbase;
  const float* Vb = V + bbase;
  float* outb = out + bbase;

  // per-lane x-pad masks for received shuffles
  float lmL = (lane == 0) ? 0.f : 1.f;
  float lmR = (lane == 63) ? 0.f : 1.f;

  // uniform row bases (clamped) + OOB masks
  const float* krow[9];
  const float* vrow[9];
  float okf[9];
#pragma unroll
  for (int dz = 0; dz < 3; ++dz)
#pragma unroll
    for (int dy = 0; dy < 3; ++dy) {
      int rr = dz * 3 + dy;
      int zz = d + dz - 1, yy = hu + dy - 1;
      bool ok = ((unsigned)zz < 64u) & ((unsigned)yy < 64u);
      int zc = zz < 0 ? 0 : (zz > 63 ? 63 : zz);
      int yc = yy < 0 ? 0 : (yy > 63 ? 63 : yy);
      krow[rr] = Kb + zc * S2 + yc * S;
      vrow[rr] = Vb + zc * S2 + yc * S;
      okf[rr] = ok ? 1.f : 0.f;
    }
  int pos = d * S2 + hu * S + lane;

  float spe[27];  // pe part (always at own lane, unmasked)
  float sC[9], sXR[9], sXL[9];
#pragma unroll
  for (int t = 0; t < 27; ++t) spe[t] = 0.f;
#pragma unroll
  for (int rr = 0; rr < 9; ++rr) { sC[rr] = 0.f; sXR[rr] = 0.f; sXL[rr] = 0.f; }

  // ---- Phase A: scores (2 shuffles per channel) ----
#pragma unroll 4
  for (int c = 0; c < CH; ++c) {
    int coff = c * S3;
    float q = Qb[coff + pos];
    float rv[9];
#pragma unroll
    for (int rr = 0; rr < 9; ++rr) rv[rr] = krow[rr][coff + lane];
    float qR = __shfl_down(q, 1);  // q of lane+1
    float qL = __shfl_up(q, 1);    // q of lane-1
#pragma unroll
    for (int rr = 0; rr < 9; ++rr) {
      sC[rr]  = fmaf(q,  rv[rr], sC[rr]);
      sXR[rr] = fmaf(qR, rv[rr], sXR[rr]);  // belongs to lane+1's left tap
      sXL[rr] = fmaf(qL, rv[rr], sXL[rr]);  // belongs to lane-1's right tap
    }
    const float* pec = pe + c * 27;  // uniform -> scalar loads
#pragma unroll
    for (int t = 0; t < 27; ++t) spe[t] = fmaf(q, pec[t], spe[t]);
  }

  // ---- assemble the 27 tap scores (18 shuffles, once) ----
  float s[27];
#pragma unroll
  for (int rr = 0; rr < 9; ++rr) {
    float lt = __shfl_up(sXR[rr], 1);    // = sum_c q[w]*K[rr][w-1]
    float rt = __shfl_down(sXL[rr], 1);  // = sum_c q[w]*K[rr][w+1]
    s[rr * 3]     = fmaf(lt * lmL, okf[rr], spe[rr * 3]);
    s[rr * 3 + 1] = fmaf(sC[rr],   okf[rr], spe[rr * 3 + 1]);
    s[rr * 3 + 2] = fmaf(rt * lmR, okf[rr], spe[rr * 3 + 2]);
  }

  // ---- softmax over 27 taps (base-2; normalization folded into weights) ----
  const float SC = 0.125f * 1.44269504088896f;
#pragma unroll
  for (int t = 0; t < 27; ++t) s[t] *= SC;
  float m = s[0];
#pragma unroll
  for (int t = 1; t < 27; ++t) m = fmaxf(m, s[t]);
  float sum = 0.f;
#pragma unroll
  for (int t = 0; t < 27; ++t) {
    s[t] = exp2f(s[t] - m);
    sum += s[t];
  }
  float inv = 1.f / sum;

  // ---- weights: fold inv + row mask; pre-shuffle cross weights ----
  float wC[9], sLs[9], sRs[9];
#pragma unroll
  for (int rr = 0; rr < 9; ++rr) {
    float f = inv * okf[rr];  // OOB rows: V-pad = 0 -> weight 0
    float wL = s[rr * 3] * f;
    wC[rr]   = s[rr * 3 + 1] * f;
    float wR = s[rr * 3 + 2] * f;
    sLs[rr] = __shfl_down(wL, 1);  // left-tap weight of lane+1
    sRs[rr] = __shfl_up(wR, 1);    // right-tap weight of lane-1
  }

  // ---- Phase B: gather V + progressive W-projection (ALL static indexing) ----
  float acc_o[CH];
#pragma unroll
  for (int o = 0; o < CH; ++o) acc_o[o] = 0.f;

#pragma unroll 2
  for (int c = 0; c < CH; ++c) {
    int coff = c * S3;
    float rv[9];
#pragma unroll
    for (int rr = 0; rr < 9; ++rr) rv[rr] = vrow[rr][coff + lane];
    float own = 0.f, cR = 0.f, cL = 0.f;
#pragma unroll
    for (int rr = 0; rr < 9; ++rr) {
      own = fmaf(wC[rr], rv[rr], own);
      cR  = fmaf(sLs[rr], rv[rr], cR);  // contribution to x of lane+1
      cL  = fmaf(sRs[rr], rv[rr], cL);  // contribution to x of lane-1
    }
    float x_c = own + __shfl_up(cR, 1) * lmL + __shfl_down(cL, 1) * lmR;
    const float* wr = WT_buf + c * CH;  // uniform, contiguous -> s_load wide
#pragma unroll
    for (int o = 0; o < CH; ++o) acc_o[o] = fmaf(wr[o], x_c, acc_o[o]);
  }

  // ---- epilogue: bias + 64 coalesced row stores (FULL unroll, static idx) ----
#pragma unroll
  for (int o = 0; o < CH; ++o) outb[o * S3 + pos] = acc_o[o] + bias[o];
}

// ---------------------------------------------------------------------------
extern "C" void kernel_launch(void* const* d_in, const int* in_sizes, int n_in,
                              void* d_out, int out_size, void* d_ws, size_t ws_size,
                              hipStream_t stream) {
  const float* Q = (const float*)d_in[0];
  const float* K = (const float*)d_in[1];
  const float* V = (const float*)d_in[2];
  const float* pe = (const float*)d_in[3];
  const float* W = (const float*)d_in[4];
  const float* bias = (const float*)d_in[5];
  float* out = (float*)d_out;

  wtrans<<<16, 256, 0, stream>>>(W);
  attn_fused<<<2048, 256, 0, stream>>>(Q, K, V, pe, bias, out);
}

// Round 10
// 275.088 us; speedup vs baseline: 1.1105x; 1.1105x over previous
//
#include <hip/hip_runtime.h>
#include <math.h>

#define CH 64
#define S 64
#define S2 (64 * 64)
#define S3 (64 * 64 * 64)

__device__ float WT_buf[CH * CH];  // W transposed: WT[c][o]

// ---------------------------------------------------------------------------
// Kernel 0: transpose W (64x64) into WT_buf (columns of W become contiguous
// rows -> wide scalar loads in the fused kernel's W-accumulation).
// ---------------------------------------------------------------------------
__global__ __launch_bounds__(256) void wtrans(const float* __restrict__ W) {
  int i = blockIdx.x * 256 + threadIdx.x;
  int o = i >> 6, c = i & 63;
  WT_buf[c * CH + o] = W[o * CH + c];
}

// ---------------------------------------------------------------------------
// Fused kernel: scores -> softmax -> V-gather -> W-projection -> out, one
// pass over inputs, barrier-free, LDS-free. One wave per (b,d,h) row.
//
// r9 lesson: 64 live accumulators -> compiler parks them in AGPRs (VGPR=72)
// and phase B drowns in v_accvgpr moves. Now the W-projection runs in TWO
// passes of 32 output channels (pass loop NOT unrolled), so only acc[32] is
// live at a time -> pure arch-VGPR allocation. V is re-gathered in pass 2
// (L2-served, +27 FMA/c) which is far cheaper than AGPR traffic.
// ---------------------------------------------------------------------------
__global__ __launch_bounds__(256) void attn_fused(const float* __restrict__ Q,
                                                  const float* __restrict__ K,
                                                  const float* __restrict__ V,
                                                  const float* __restrict__ pe,
                                                  const float* __restrict__ bias,
                                                  float* __restrict__ out) {
  int tid = threadIdx.x;
  int lane = tid & 63;
  int wv = tid >> 6;

  // XCD-aware bijective swizzle (2048 % 8 == 0)
  int raw = blockIdx.x;
  int sw = (raw & 7) * 256 + (raw >> 3);
  int b = sw >> 10;
  int r = sw & 1023;
  int d = r >> 4;                                             // 0..63
  int hu = __builtin_amdgcn_readfirstlane((r & 15) * 4 + wv);  // 0..63, uniform

  size_t bbase = (size_t)b << 24;
  const float* Qb = Q + bbase;
  const float* Kb = K + bbase;
  const float* Vb = V + bbase;
  float* outb = out + bbase;

  // per-lane x-pad masks for received shuffles
  float lmL = (lane == 0) ? 0.f : 1.f;
  float lmR = (lane == 63) ? 0.f : 1.f;

  // uniform row bases (clamped) + OOB masks
  const float* krow[9];
  const float* vrow[9];
  float okf[9];
#pragma unroll
  for (int dz = 0; dz < 3; ++dz)
#pragma unroll
    for (int dy = 0; dy < 3; ++dy) {
      int rr = dz * 3 + dy;
      int zz = d + dz - 1, yy = hu + dy - 1;
      bool ok = ((unsigned)zz < 64u) & ((unsigned)yy < 64u);
      int zc = zz < 0 ? 0 : (zz > 63 ? 63 : zz);
      int yc = yy < 0 ? 0 : (yy > 63 ? 63 : yy);
      krow[rr] = Kb + zc * S2 + yc * S;
      vrow[rr] = Vb + zc * S2 + yc * S;
      okf[rr] = ok ? 1.f : 0.f;
    }
  int pos = d * S2 + hu * S + lane;

  float spe[27];  // pe part (always at own lane, unmasked)
  float sC[9], sXR[9], sXL[9];
#pragma unroll
  for (int t = 0; t < 27; ++t) spe[t] = 0.f;
#pragma unroll
  for (int rr = 0; rr < 9; ++rr) { sC[rr] = 0.f; sXR[rr] = 0.f; sXL[rr] = 0.f; }

  // ---- Phase A: scores (2 shuffles per channel) ----
#pragma unroll 4
  for (int c = 0; c < CH; ++c) {
    int coff = c * S3;
    float q = Qb[coff + pos];
    float rv[9];
#pragma unroll
    for (int rr = 0; rr < 9; ++rr) rv[rr] = krow[rr][coff + lane];
    float qR = __shfl_down(q, 1);  // q of lane+1
    float qL = __shfl_up(q, 1);    // q of lane-1
#pragma unroll
    for (int rr = 0; rr < 9; ++rr) {
      sC[rr]  = fmaf(q,  rv[rr], sC[rr]);
      sXR[rr] = fmaf(qR, rv[rr], sXR[rr]);  // belongs to lane+1's left tap
      sXL[rr] = fmaf(qL, rv[rr], sXL[rr]);  // belongs to lane-1's right tap
    }
    const float* pec = pe + c * 27;  // uniform -> scalar loads
#pragma unroll
    for (int t = 0; t < 27; ++t) spe[t] = fmaf(q, pec[t], spe[t]);
  }

  // ---- assemble the 27 tap scores (18 shuffles, once) ----
  float s[27];
#pragma unroll
  for (int rr = 0; rr < 9; ++rr) {
    float lt = __shfl_up(sXR[rr], 1);    // = sum_c q[w]*K[rr][w-1]
    float rt = __shfl_down(sXL[rr], 1);  // = sum_c q[w]*K[rr][w+1]
    s[rr * 3]     = fmaf(lt * lmL, okf[rr], spe[rr * 3]);
    s[rr * 3 + 1] = fmaf(sC[rr],   okf[rr], spe[rr * 3 + 1]);
    s[rr * 3 + 2] = fmaf(rt * lmR, okf[rr], spe[rr * 3 + 2]);
  }

  // ---- softmax over 27 taps (base-2; normalization folded into weights) ----
  const float SC = 0.125f * 1.44269504088896f;
#pragma unroll
  for (int t = 0; t < 27; ++t) s[t] *= SC;
  float m = s[0];
#pragma unroll
  for (int t = 1; t < 27; ++t) m = fmaxf(m, s[t]);
  float sum = 0.f;
#pragma unroll
  for (int t = 0; t < 27; ++t) {
    s[t] = exp2f(s[t] - m);
    sum += s[t];
  }
  float inv = 1.f / sum;

  // ---- weights: fold inv + row mask; pre-shuffle cross weights ----
  float wC[9], sLs[9], sRs[9];
#pragma unroll
  for (int rr = 0; rr < 9; ++rr) {
    float f = inv * okf[rr];  // OOB rows: V-pad = 0 -> weight 0
    float wL = s[rr * 3] * f;
    wC[rr]   = s[rr * 3 + 1] * f;
    float wR = s[rr * 3 + 2] * f;
    sLs[rr] = __shfl_down(wL, 1);  // left-tap weight of lane+1
    sRs[rr] = __shfl_up(wR, 1);    // right-tap weight of lane-1
  }

  // ---- Phase B: two passes of 32 output channels; only acc[32] live ----
#pragma unroll 1
  for (int p = 0; p < 2; ++p) {
    int obase = p * 32;
    float acc[32];
#pragma unroll
    for (int j = 0; j < 32; ++j) acc[j] = 0.f;

#pragma unroll 2
    for (int c = 0; c < CH; ++c) {
      int coff = c * S3;
      float rv[9];
#pragma unroll
      for (int rr = 0; rr < 9; ++rr) rv[rr] = vrow[rr][coff + lane];
      float own = 0.f, cR = 0.f, cL = 0.f;
#pragma unroll
      for (int rr = 0; rr < 9; ++rr) {
        own = fmaf(wC[rr], rv[rr], own);
        cR  = fmaf(sLs[rr], rv[rr], cR);  // contribution to x of lane+1
        cL  = fmaf(sRs[rr], rv[rr], cL);  // contribution to x of lane-1
      }
      float x_c = own + __shfl_up(cR, 1) * lmL + __shfl_down(cL, 1) * lmR;
      const float* wr = WT_buf + c * CH + obase;  // uniform -> wide s_load
#pragma unroll
      for (int j = 0; j < 32; ++j) acc[j] = fmaf(wr[j], x_c, acc[j]);
    }

    // epilogue for this half: bias + 32 coalesced row stores (static idx)
#pragma unroll
    for (int j = 0; j < 32; ++j)
      outb[(obase + j) * S3 + pos] = acc[j] + bias[obase + j];
  }
}

// ---------------------------------------------------------------------------
extern "C" void kernel_launch(void* const* d_in, const int* in_sizes, int n_in,
                              void* d_out, int out_size, void* d_ws, size_t ws_size,
                              hipStream_t stream) {
  const float* Q = (const float*)d_in[0];
  const float* K = (const float*)d_in[1];
  const float* V = (const float*)d_in[2];
  const float* pe = (const float*)d_in[3];
  const float* W = (const float*)d_in[4];
  const float* bias = (const float*)d_in[5];
  float* out = (float*)d_out;

  wtrans<<<16, 256, 0, stream>>>(W);
  attn_fused<<<2048, 256, 0, stream>>>(Q, K, V, pe, bias, out);
}